// Round 10
// baseline (207.820 us; speedup 1.0000x reference)
//
#include <hip/hip_runtime.h>
#include <stdint.h>
#include <stddef.h>

// Problem dims (fixed by reference)
#define BB 8192
#define TT 26
#define VV 23
#define EE 100
#define HH 128
#define LL 64

typedef __attribute__((ext_vector_type(8))) short bf16x8;  // 8 bf16 = 4 VGPRs
typedef __attribute__((ext_vector_type(4))) float f32x4;   // MFMA 16x16 C/D

#define MFMA(a, b, c) __builtin_amdgcn_mfma_f32_16x16x32_bf16((a), (b), (c), 0, 0, 0)

// ws: only the one-hot table lives here now (24 ct * 1024 B)
#define OFF_TBL 0ull

// Dynamic-LDS partition (bytes)
#define L_LW    0              // LSTM h-half weight frags: 112 KB (28ct * 4kc * 1024)
#define L_HF    114688         // GRU y/h dbuf: 2 buf * 2 sub * 4096
#define L_LH    131072         // LSTM h dbuf: 2 buf * 2 sub * 4096
#define L_IDX   147456         // token idx: TT*32
#define L_TOTAL 148288

__device__ __forceinline__ void force_frag(bf16x8& v) { asm volatile("" : "+v"(v)); }

// Exact RNE (one-time weight conversion)
__device__ __forceinline__ unsigned short f2bf(float f) {
  union { float f; unsigned u; } v; v.f = f;
  unsigned u = v.u;
  return (unsigned short)((u + 0x7FFFu + ((u >> 16) & 1u)) >> 16);
}
// Fast in-loop convert (round-half-up)
__device__ __forceinline__ unsigned short f2bf_fast(float f) {
  union { float f; unsigned u; } v; v.f = f;
  return (unsigned short)((v.u + 0x8000u) >> 16);
}
#define LOG2E 1.4426950408889634f
__device__ __forceinline__ float sigm(float x) {
  return __builtin_amdgcn_rcpf(1.0f + __builtin_amdgcn_exp2f(-x * LOG2E));
}
__device__ __forceinline__ float tanh_(float x) {
  return __builtin_fmaf(-2.0f,
      __builtin_amdgcn_rcpf(1.0f + __builtin_amdgcn_exp2f(x * (2.0f * LOG2E))), 1.0f);
}

// Build one bf16x8 B-frag row-chunk from 8 contiguous fp32 (aligned case)
__device__ __forceinline__ bf16x8 ldfrag8(const float* __restrict__ p) {
  f32x4 a = *(const f32x4*)(p);
  f32x4 b = *(const f32x4*)(p + 4);
  bf16x8 r;
#pragma unroll
  for (int j = 0; j < 4; j++) { r[j] = (short)f2bf(a[j]); r[4 + j] = (short)f2bf(b[j]); }
  return r;
}

// =====================================================================
// K0: one-hot table build (emb[k]@gru_wih[n] + gru_bih[n]), LDS-staged.
// Writes B-frags: entry = ct*512 + lane*8 + j; n = ct*16+(lane&15),
// k = ((lane>>4)&3)*8 + j (vocab, pad>=23 -> 0).
// =====================================================================
__global__ __launch_bounds__(512) void prep_table_kernel(
    const float* __restrict__ emb, const float* __restrict__ gru_wih,
    const float* __restrict__ gru_bih, char* __restrict__ ws)
{
  __shared__ float emb_s[VV * EE];
  __shared__ float wih_s[16 * EE];
  __shared__ float bih_s[16];
  const int tid = threadIdx.x;
  const int ct  = blockIdx.x;           // 0..23
  const int n0  = ct * 16;

  for (int i = tid; i < VV * EE; i += 512) emb_s[i] = emb[i];
  for (int i = tid; i < 16 * EE; i += 512) wih_s[i] = gru_wih[n0 * EE + i];
  if (tid < 16) bih_s[tid] = gru_bih[n0 + tid];
  __syncthreads();

  const int j    = tid & 7;
  const int lane = (tid >> 3) & 63;
  const int n16  = lane & 15;
  const int k    = ((lane >> 4) & 3) * 8 + j;
  float v = 0.0f;
  if (k < VV) {
    const float* ep = emb_s + k * EE;
    const float* wp = wih_s + n16 * EE;
    float s0 = 0.f, s1 = 0.f, s2 = 0.f, s3 = 0.f;
#pragma unroll 5
    for (int m = 0; m < EE; m += 4) {
      s0 += ep[m] * wp[m];         s1 += ep[m + 1] * wp[m + 1];
      s2 += ep[m + 2] * wp[m + 2]; s3 += ep[m + 3] * wp[m + 3];
    }
    v = bih_s[n16] + ((s0 + s1) + (s2 + s3));
  }
  *(unsigned short*)(ws + OFF_TBL + (size_t)(ct * 512 + tid) * 2) = f2bf(v);
}

// =====================================================================
// K1: FUSED gru+lstm+logits, single pass. 256 blocks x 1024 thr
// (16 waves), 32 rows/block (2 sub-btiles of 16). All weight frags
// built inline from raw fp32 weights (contiguous-8 gathers); LSTM
// h-half weights (112 KB) staged into dynamic LDS. 28 phases:
//   waves 0-7  (GRU):    step p      y(p)   -> hfrag[(p+1)&1]
//   waves 8-14 (LSTM):   step p-1    h(p-1) -> lhbuf[p&1]
//   wave 15    (logits): step p-2    -> out
// =====================================================================
__global__ __launch_bounds__(1024, 4) void fused_kernel(
    const float* __restrict__ z, const int* __restrict__ x_in,
    const float* __restrict__ fc_z_b, const float* __restrict__ gru_bhh,
    const float* __restrict__ gru_whh, const float* __restrict__ fc_z_w,
    const float* __restrict__ lstm_wih, const float* __restrict__ lstm_whh,
    const float* __restrict__ lstm_bih, const float* __restrict__ lstm_bhh,
    const float* __restrict__ out_w, const float* __restrict__ out_b,
    const unsigned short* __restrict__ tbl, float* __restrict__ out)
{
  extern __shared__ char smem[];
  char*           lwlds   = smem + L_LW;
  char*           hfrag   = smem + L_HF;    // [buf*8192 + sub*4096]
  char*           lhbuf   = smem + L_LH;
  unsigned char*  idx_lds = (unsigned char*)(smem + L_IDX);

  const int tid  = threadIdx.x;
  const int wv   = tid >> 6;        // 0..15
  const int lane = tid & 63;
  const int l15  = lane & 15;
  const int q    = (lane >> 4) & 3;
  const int blk  = blockIdx.x;      // 0..255

  // ---- cooperative init: zero LSTM h state; stage h-half weights ----
  for (int i = tid; i < 8192; i += 1024)
    ((unsigned short*)lhbuf)[i] = 0;
  for (int f = tid; f < 7168; f += 1024) {        // 7168 b128 chunks = 112 KB
    int frag_i = f >> 6, within = f & 63;
    int ct = frag_i >> 2, kcl = frag_i & 3;
    int row = ct * 16 + (within & 15);
    int g = row / 112, c = row - g * 112;
    int k0 = kcl * 32 + ((within >> 4) & 3) * 8;
    bf16x8 vv;
#pragma unroll
    for (int j = 0; j < 8; j++) {
      int k = k0 + j;
      float v = (c < EE && k < EE) ? lstm_whh[(g * EE + c) * EE + k] : 0.0f;
      vv[j] = (short)f2bf(v);
    }
    *(bf16x8*)(lwlds + (size_t)frag_i * 1024 + within * 16) = vv;
  }

  if (wv < 8) {
    // ================= GRU role =================
    {
      int rid = wv * 64 + lane;     // 0..511
      for (int i = rid; i < TT * 32; i += 512) {
        int t = i >> 5, r = i & 31;
        idx_lds[i] = (unsigned char)x_in[(blk * 32 + r) * TT + t];
      }
    }
    const int col = wv * 16 + l15;
    // weight frags inline: gw[g][kc] lane = gru_whh[n][k0..k0+7]
    bf16x8 gw[3][4], tw[3];
#pragma unroll
    for (int g = 0; g < 3; g++) {
      int n = (g * 8 + wv) * 16 + l15;            // row in (384,128)
#pragma unroll
      for (int kc = 0; kc < 4; kc++) {
        gw[g][kc] = ldfrag8(gru_whh + (size_t)n * HH + kc * 32 + q * 8);
        force_frag(gw[g][kc]);
      }
      tw[g] = *(const bf16x8*)(tbl + (size_t)(g * 8 + wv) * 512 + lane * 8);
      force_frag(tw[g]);
    }
    const float b_r = gru_bhh[0 * HH + col];
    const float b_z = gru_bhh[1 * HH + col];
    const float b_n = gru_bhh[2 * HH + col];
    const int wbase = (col >> 5) * 512 + ((col >> 3) & 3) * 128 + (col & 7);

    // h0 = tanh(z @ fc_z_w^T + fc_z_b), both subs
    float h[2][4];
    {
      bf16x8 fw0 = ldfrag8(fc_z_w + (size_t)col * LL + 0 * 32 + q * 8);
      bf16x8 fw1 = ldfrag8(fc_z_w + (size_t)col * LL + 1 * 32 + q * 8);
      float fzb = fc_z_b[col];
#pragma unroll
      for (int s = 0; s < 2; s++) {
        const float* zp = z + (size_t)(blk * 32 + s * 16 + l15) * LL + q * 8;
        f32x4 z0 = *(const f32x4*)(zp);
        f32x4 z1 = *(const f32x4*)(zp + 4);
        f32x4 z2 = *(const f32x4*)(zp + 32);
        f32x4 z3 = *(const f32x4*)(zp + 36);
        bf16x8 za0, za1;
#pragma unroll
        for (int j = 0; j < 4; j++) {
          za0[j]     = (short)f2bf(z0[j]);
          za0[4 + j] = (short)f2bf(z1[j]);
          za1[j]     = (short)f2bf(z2[j]);
          za1[4 + j] = (short)f2bf(z3[j]);
        }
        f32x4 acc = {fzb, fzb, fzb, fzb};
        acc = MFMA(za0, fw0, acc);
        acc = MFMA(za1, fw1, acc);
#pragma unroll
        for (int i = 0; i < 4; i++) {
          h[s][i] = tanh_(acc[i]);
          ((unsigned short*)(hfrag + s * 4096))[wbase + (q * 4 + i) * 8] = f2bf_fast(h[s][i]);
        }
      }
    }
    __syncthreads();                              // barrier A

    for (int p = 0; p < TT + 2; p++) {
      if (p < TT) {
#pragma unroll
        for (int s = 0; s < 2; s++) {
          int iv = idx_lds[p * 32 + s * 16 + l15];
          bf16x8 oh;
#pragma unroll
          for (int j = 0; j < 8; j++)
            oh[j] = (short)((iv == q * 8 + j) ? 0x3F80 : 0);

          f32x4 ar  = {b_r, b_r, b_r, b_r};
          f32x4 az  = {b_z, b_z, b_z, b_z};
          f32x4 ahn = {b_n, b_n, b_n, b_n};
          f32x4 axn = {0.0f, 0.0f, 0.0f, 0.0f};
          ar  = MFMA(oh, tw[0], ar);
          az  = MFMA(oh, tw[1], az);
          axn = MFMA(oh, tw[2], axn);

          bf16x8 a[4];
#pragma unroll
          for (int kc = 0; kc < 4; kc++)
            a[kc] = *(const bf16x8*)(hfrag + (p & 1) * 8192 + s * 4096 + kc * 1024 + lane * 16);
#pragma unroll
          for (int kc = 0; kc < 4; kc++) {
            ar  = MFMA(a[kc], gw[0][kc], ar);
            az  = MFMA(a[kc], gw[1][kc], az);
            ahn = MFMA(a[kc], gw[2][kc], ahn);
          }
#pragma unroll
          for (int i = 0; i < 4; i++) {
            float r  = sigm(ar[i]);
            float zg = sigm(az[i]);
            float n  = tanh_(__builtin_fmaf(r, ahn[i], axn[i]));
            h[s][i] = __builtin_fmaf(zg, h[s][i] - n, n);
            ((unsigned short*)(hfrag + ((p + 1) & 1) * 8192 + s * 4096))[wbase + (q * 4 + i) * 8]
                = f2bf_fast(h[s][i]);
          }
        }
      }
      __syncthreads();
    }
  } else if (wv < 15) {
    // ================= LSTM role =================
    const int tile = wv - 8;        // 0..6
    const int col  = tile * 16 + l15;   // = c (row within gate), < 112
    bf16x8 lwy[4][4];
#pragma unroll
    for (int g = 0; g < 4; g++)
#pragma unroll
      for (int kc = 0; kc < 4; kc++) {
        bf16x8 w;
        if (col < EE) w = ldfrag8(lstm_wih + (size_t)(g * EE + col) * HH + kc * 32 + q * 8);
        else { bf16x8 zz = {0,0,0,0,0,0,0,0}; w = zz; }
        lwy[g][kc] = w;
        force_frag(lwy[g][kc]);
      }
    float b[4];
#pragma unroll
    for (int g = 0; g < 4; g++)
      b[g] = (col < EE) ? (lstm_bih[g * EE + col] + lstm_bhh[g * EE + col]) : 0.0f;
    const int wbase = (col >> 5) * 512 + ((col >> 3) & 3) * 128 + (col & 7);
    float c[2][4] = {{0, 0, 0, 0}, {0, 0, 0, 0}};
    __syncthreads();                              // barrier A

    for (int p = 0; p < TT + 2; p++) {
      if (p >= 1 && p <= TT) {
#pragma unroll
        for (int s = 0; s < 2; s++) {
          f32x4 ai = {b[0], b[0], b[0], b[0]};
          f32x4 af = {b[1], b[1], b[1], b[1]};
          f32x4 ag = {b[2], b[2], b[2], b[2]};
          f32x4 ao = {b[3], b[3], b[3], b[3]};
          // y-half: reg weights, y(p-1) from hfrag
#pragma unroll
          for (int kc = 0; kc < 4; kc++) {
            bf16x8 ya = *(const bf16x8*)(hfrag + (p & 1) * 8192 + s * 4096 + kc * 1024 + lane * 16);
            ai = MFMA(ya, lwy[0][kc], ai);
            af = MFMA(ya, lwy[1][kc], af);
            ag = MFMA(ya, lwy[2][kc], ag);
            ao = MFMA(ya, lwy[3][kc], ao);
          }
          // h-half: LDS weights
#pragma unroll
          for (int kc = 0; kc < 4; kc++) {
            bf16x8 ha = *(const bf16x8*)(lhbuf + ((p - 1) & 1) * 8192 + s * 4096 + kc * 1024 + lane * 16);
            const char* wb = lwlds + (size_t)(tile * 4 + kc) * 1024 + lane * 16;
            bf16x8 w0 = *(const bf16x8*)(wb);
            bf16x8 w1 = *(const bf16x8*)(wb + 28672);     // gate stride 7*4*1024
            bf16x8 w2 = *(const bf16x8*)(wb + 2 * 28672);
            bf16x8 w3 = *(const bf16x8*)(wb + 3 * 28672);
            ai = MFMA(ha, w0, ai);
            af = MFMA(ha, w1, af);
            ag = MFMA(ha, w2, ag);
            ao = MFMA(ha, w3, ao);
          }
#pragma unroll
          for (int i = 0; i < 4; i++) {
            float ii = sigm(ai[i]), ff = sigm(af[i]);
            float gg = tanh_(ag[i]), oo = sigm(ao[i]);
            float cn = __builtin_fmaf(ff, c[s][i], ii * gg);
            c[s][i] = cn;
            ((unsigned short*)(lhbuf + (p & 1) * 8192 + s * 4096))[wbase + (q * 4 + i) * 8]
                = f2bf_fast(oo * tanh_(cn));
          }
        }
      }
      __syncthreads();
    }
  } else {
    // ================= logits role =================
    bf16x8 ow[2][4];
#pragma unroll
    for (int ct = 0; ct < 2; ct++) {
      int n = ct * 16 + l15;
#pragma unroll
      for (int kc = 0; kc < 4; kc++) {
        bf16x8 w;
        if (n < VV && kc < 3) {
          w = ldfrag8(out_w + (size_t)n * EE + kc * 32 + q * 8);
        } else {
#pragma unroll
          for (int j = 0; j < 8; j++) {
            int k = kc * 32 + q * 8 + j;
            float v = (n < VV && k < EE) ? out_w[(size_t)n * EE + k] : 0.0f;
            w[j] = (short)f2bf(v);
          }
        }
        ow[ct][kc] = w;
        force_frag(ow[ct][kc]);
      }
    }
    float ob[2];
#pragma unroll
    for (int ct = 0; ct < 2; ct++) {
      int cv = ct * 16 + l15;
      ob[ct] = (cv < VV) ? out_b[cv] : 0.0f;
    }
    __syncthreads();                              // barrier A

    for (int p = 0; p < TT + 2; p++) {
      if (p >= 2) {
        const int t = p - 2;
#pragma unroll
        for (int s = 0; s < 2; s++) {
          bf16x8 ha[4];
#pragma unroll
          for (int kc = 0; kc < 4; kc++)
            ha[kc] = *(const bf16x8*)(lhbuf + ((p - 1) & 1) * 8192 + s * 4096 + kc * 1024 + lane * 16);
#pragma unroll
          for (int ct = 0; ct < 2; ct++) {
            f32x4 acc = {ob[ct], ob[ct], ob[ct], ob[ct]};
#pragma unroll
            for (int kc = 0; kc < 4; kc++)
              acc = MFMA(ha[kc], ow[ct][kc], acc);
            int cv = ct * 16 + l15;
            if (cv < VV) {
#pragma unroll
              for (int i = 0; i < 4; i++) {
                int rowg = blk * 32 + s * 16 + q * 4 + i;
                out[((size_t)rowg * TT + t) * VV + cv] = acc[i];
              }
            }
          }
        }
      }
      __syncthreads();
    }
  }
}

extern "C" void kernel_launch(void* const* d_in, const int* in_sizes, int n_in,
                              void* d_out, int out_size, void* d_ws, size_t ws_size,
                              hipStream_t stream) {
  (void)in_sizes; (void)n_in; (void)out_size; (void)ws_size;
  const float* z        = (const float*)d_in[0];
  const int*   x_in     = (const int*)  d_in[1];
  const float* emb      = (const float*)d_in[2];
  const float* fc_z_w   = (const float*)d_in[3];
  const float* fc_z_b   = (const float*)d_in[4];
  const float* gru_wih  = (const float*)d_in[5];
  const float* gru_whh  = (const float*)d_in[6];
  const float* gru_bih  = (const float*)d_in[7];
  const float* gru_bhh  = (const float*)d_in[8];
  const float* lstm_wih = (const float*)d_in[9];
  const float* lstm_whh = (const float*)d_in[10];
  const float* lstm_bih = (const float*)d_in[11];
  const float* lstm_bhh = (const float*)d_in[12];
  const float* out_w    = (const float*)d_in[13];
  const float* out_b    = (const float*)d_in[14];
  char*  ws  = (char*)d_ws;
  float* out = (float*)d_out;

  const unsigned short* tblp = (const unsigned short*)(ws + OFF_TBL);

  hipFuncSetAttribute((const void*)fused_kernel,
                      hipFuncAttributeMaxDynamicSharedMemorySize, L_TOTAL);

  prep_table_kernel<<<24, 512, 0, stream>>>(emb, gru_wih, gru_bih, ws);
  fused_kernel<<<256, 1024, L_TOTAL, stream>>>(z, x_in, fc_z_b, gru_bhh,
                                               gru_whh, fc_z_w,
                                               lstm_wih, lstm_whh,
                                               lstm_bih, lstm_bhh,
                                               out_w, out_b, tblp, out);
}